// Round 1
// baseline (546.582 us; speedup 1.0000x reference)
//
#include <hip/hip_runtime.h>
#include <hip/hip_bf16.h>
#include <stdint.h>

#define B_  16
#define N_  1024
#define C_  1024
#define H_  16
#define Dh  64
#define M_  (B_*N_)
#define QSCALE (0.125f * 1.44269504f)   // softmax scale * log2(e), folded into q

typedef __attribute__((ext_vector_type(8))) short short8;
typedef __attribute__((ext_vector_type(4))) float f32x4;

__device__ __forceinline__ ushort f2bf(float f) {
  union { float f; uint32_t u; } v; v.f = f;
  uint32_t u = v.u;
  u += 0x7fffu + ((u >> 16) & 1u);      // RNE
  return (ushort)(u >> 16);
}

__device__ __forceinline__ float exp2fast(float x) {
#if __has_builtin(__builtin_amdgcn_exp2f)
  return __builtin_amdgcn_exp2f(x);
#else
  return exp2f(x);
#endif
}

__device__ __forceinline__ void gload_lds16(const ushort* g, ushort* l) {
  __builtin_amdgcn_global_load_lds((const __attribute__((address_space(1))) void*)g,
                                   (__attribute__((address_space(3))) void*)l, 16, 0, 0);
}

// ---------------- cast fp32 -> bf16 (vectorized, optional scale) ----------------
__global__ void cast_bf16_k(const float* __restrict__ src, ushort* __restrict__ dst,
                            int n4, float scale) {
  int i = blockIdx.x * blockDim.x + threadIdx.x;
  int stride = gridDim.x * blockDim.x;
  for (; i < n4; i += stride) {
    float4 v = reinterpret_cast<const float4*>(src)[i];
    ushort4 o;
    o.x = f2bf(v.x * scale);
    o.y = f2bf(v.y * scale);
    o.z = f2bf(v.z * scale);
    o.w = f2bf(v.w * scale);
    reinterpret_cast<ushort4*>(dst)[i] = o;
  }
}

// ---------------- 128x128 bf16 GEMM, B^T layout (Bm[n][k]), BK=32 ----------------
// MODE 0: out = A@B^T            -> oq as bf16 [M][128]   (lora stage-1)
// MODE 1: qkv + bias + lora tail -> scatter q/k/v bf16 (B,H,N,D); q scaled by QSCALE
// MODE 2: out = A@B^T + bias     -> of fp32 [M][ldo]      (final proj)
template<int MODE>
__global__ __launch_bounds__(256)
void gemm128(const ushort* __restrict__ A, int lda,
             const ushort* __restrict__ Bm, int ldb,
             const float* __restrict__ bias,
             const ushort* __restrict__ A2,
             const ushort* __restrict__ B2k, const ushort* __restrict__ B2v,
             ushort* __restrict__ oq, ushort* __restrict__ ok, ushort* __restrict__ ov,
             float* __restrict__ of, int ldo)
{
  __shared__ ushort sA[2][128*32];
  __shared__ ushort sB[2][128*32];
  const int t = threadIdx.x;
  const int lane = t & 63, w = t >> 6;
  const int wr = w >> 1, wc = w & 1;
  const int r = lane & 15, g = lane >> 4;
  const int m0 = blockIdx.x * 128, n0 = blockIdx.y * 128;

  const int s = n0 >> 10;
  int nt = 32;
  const ushort* A2b = nullptr; const ushort* B2 = nullptr; int n0loc = 0;
  if (MODE == 1 && s > 0) {
    nt = 34;                              // +2 tiles of K=32 for the LoRA rank-64 tail
    A2b = A2 + (s == 2 ? 64 : 0);         // tkv cols: k-lora 0..63, v-lora 64..127
    B2 = (s == 1) ? B2k : B2v;
    n0loc = n0 - (s << 10);
  }

  auto stage = [&](int buf, int tt) {
    const ushort* Ab; const ushort* Bb; int ldaT, ldbT;
    if (tt < 32) { Ab = A + m0*lda + tt*32; ldaT = lda; Bb = Bm + n0*ldb + tt*32; ldbT = ldb; }
    else { Ab = A2b + m0*128 + (tt-32)*32; ldaT = 128; Bb = B2 + n0loc*64 + (tt-32)*32; ldbT = 64; }
    #pragma unroll
    for (int i = 0; i < 2; ++i) {
      int c = i*256 + t;                  // 512 chunks of 16B per tile
      gload_lds16(Ab + (c>>2)*ldaT + (c&3)*8, &sA[buf][c*8]);
      gload_lds16(Bb + (c>>2)*ldbT + (c&3)*8, &sB[buf][c*8]);
    }
  };

  f32x4 acc[4][4];
  #pragma unroll
  for (int i=0;i<4;++i)
    #pragma unroll
    for (int j=0;j<4;++j) acc[i][j] = (f32x4){0.f,0.f,0.f,0.f};

  stage(0, 0);
  __syncthreads();
  for (int tt = 0; tt < nt; ++tt) {
    int cur = tt & 1;
    if (tt + 1 < nt) stage(cur ^ 1, tt + 1);
    short8 af[4], bfr[4];
    #pragma unroll
    for (int i=0;i<4;++i) af[i]  = *(const short8*)&sA[cur][(wr*64 + i*16 + r)*32 + g*8];
    #pragma unroll
    for (int j=0;j<4;++j) bfr[j] = *(const short8*)&sB[cur][(wc*64 + j*16 + r)*32 + g*8];
    #pragma unroll
    for (int i=0;i<4;++i)
      #pragma unroll
      for (int j=0;j<4;++j)
        acc[i][j] = __builtin_amdgcn_mfma_f32_16x16x32_bf16(af[i], bfr[j], acc[i][j], 0,0,0);
    __syncthreads();
  }

  #pragma unroll
  for (int i=0;i<4;++i) {
    #pragma unroll
    for (int j=0;j<4;++j) {
      #pragma unroll
      for (int rr=0;rr<4;++rr) {
        int m = m0 + wr*64 + i*16 + g*4 + rr;
        int n = n0 + wc*64 + j*16 + r;
        float v = acc[i][j][rr];
        if (MODE == 0) {
          oq[m*128 + n] = f2bf(v);
        } else if (MODE == 1) {
          v += bias[n];
          int b = m >> 10, nq = m & 1023;
          int c = n & 1023, h = c >> 6, d = c & 63;
          int idx = ((b*H_ + h)*N_ + nq)*Dh + d;
          if (s == 0)      oq[idx] = f2bf(v * QSCALE);
          else if (s == 1) ok[idx] = f2bf(v);
          else             ov[idx] = f2bf(v);
        } else {
          of[m*ldo + n] = v + bias[n];
        }
      }
    }
  }
}

// ---------------- flash attention: 4 waves x 16 q-rows, KV tiles of 64 ----------------
__global__ __launch_bounds__(256)
void flash_attn(const ushort* __restrict__ qb, const ushort* __restrict__ kb,
                const ushort* __restrict__ vb, ushort* __restrict__ out)
{
  __shared__ ushort Kt[64*64];     // row-major [k][d], 16B-chunk XOR-swizzled per row
  __shared__ ushort Vt[64*72];     // transposed [d][k], stride 72 (pad)
  __shared__ ushort Pl[4][16*72];  // per-wave P, stride 72
  const int t = threadIdx.x, w = t >> 6, lane = t & 63;
  const int r = lane & 15, g = lane >> 4;
  const int bh = blockIdx.x >> 4, qt = blockIdx.x & 15;
  const int b = bh >> 4, h = bh & 15;
  const ushort* Q = qb + bh * (N_*Dh);
  const ushort* K = kb + bh * (N_*Dh);
  const ushort* V = vb + bh * (N_*Dh);
  const int q0 = qt*64 + w*16;

  short8 qf[2];
  #pragma unroll
  for (int hh=0; hh<2; ++hh) qf[hh] = *(const short8*)&Q[(q0 + r)*Dh + hh*32 + g*8];

  f32x4 o[4];
  #pragma unroll
  for (int i=0;i<4;++i) o[i] = (f32x4){0.f,0.f,0.f,0.f};
  float mrun[4] = {-1e30f,-1e30f,-1e30f,-1e30f};
  float lrun[4] = {0.f,0.f,0.f,0.f};

  for (int kt = 0; kt < 16; ++kt) {
    // stage K tile, source-preswizzled so LDS stays linear for global_load_lds
    #pragma unroll
    for (int i=0;i<2;++i) {
      int ch = i*256 + t;
      int row = ch >> 3, sc = ch & 7;
      int c = sc ^ (row & 7);
      gload_lds16(&K[(kt*64 + row)*Dh + c*8], &Kt[ch*8]);
    }
    // stage V transposed (reg-staged)
    #pragma unroll
    for (int i=0;i<2;++i) {
      int ch = i*256 + t;
      int row = ch >> 3, dc = ch & 7;
      short8 v8 = *(const short8*)&V[(kt*64 + row)*Dh + dc*8];
      #pragma unroll
      for (int j=0;j<8;++j) Vt[(dc*8 + j)*72 + row] = (ushort)v8[j];
    }
    __syncthreads();

    // S = Q @ K^T (log2-domain, scale pre-folded into q)
    f32x4 sfr[4];
    #pragma unroll
    for (int kf=0; kf<4; ++kf) {
      sfr[kf] = (f32x4){0.f,0.f,0.f,0.f};
      int krow = kf*16 + r;
      #pragma unroll
      for (int hh=0; hh<2; ++hh) {
        int slot = (hh*4 + g) ^ (krow & 7);
        short8 kfrag = *(const short8*)&Kt[krow*64 + slot*8];
        sfr[kf] = __builtin_amdgcn_mfma_f32_16x16x32_bf16(qf[hh], kfrag, sfr[kf], 0,0,0);
      }
    }

    // online softmax (wave-parallel: shfl_xor over the 16 lanes sharing rows)
    float fac[4], psum[4];
    #pragma unroll
    for (int rr=0; rr<4; ++rr) {
      float mx = fmaxf(fmaxf(sfr[0][rr], sfr[1][rr]), fmaxf(sfr[2][rr], sfr[3][rr]));
      #pragma unroll
      for (int d = 1; d < 16; d <<= 1) mx = fmaxf(mx, __shfl_xor(mx, d));
      float nm = fmaxf(mrun[rr], mx);
      fac[rr] = exp2fast(mrun[rr] - nm);
      mrun[rr] = nm;
      float ps = 0.f;
      #pragma unroll
      for (int kf=0; kf<4; ++kf) {
        float p = exp2fast(sfr[kf][rr] - nm);
        Pl[w][(g*4 + rr)*72 + kf*16 + r] = f2bf(p);
        ps += p;
      }
      #pragma unroll
      for (int d = 1; d < 16; d <<= 1) ps += __shfl_xor(ps, d);
      psum[rr] = ps;
    }
    #pragma unroll
    for (int rr=0; rr<4; ++rr) lrun[rr] = lrun[rr]*fac[rr] + psum[rr];
    #pragma unroll
    for (int df=0; df<4; ++df)
      #pragma unroll
      for (int rr=0; rr<4; ++rr) o[df][rr] *= fac[rr];

    // O += P @ V   (P via per-wave LDS; DS pipe is in-order per wave)
    short8 pa[2];
    #pragma unroll
    for (int hh=0; hh<2; ++hh) pa[hh] = *(const short8*)&Pl[w][r*72 + hh*32 + g*8];
    #pragma unroll
    for (int df=0; df<4; ++df) {
      #pragma unroll
      for (int hh=0; hh<2; ++hh) {
        short8 vfrag = *(const short8*)&Vt[(df*16 + r)*72 + hh*32 + g*8];
        o[df] = __builtin_amdgcn_mfma_f32_16x16x32_bf16(pa[hh], vfrag, o[df], 0,0,0);
      }
    }
    __syncthreads();
  }

  #pragma unroll
  for (int rr=0; rr<4; ++rr) {
    float inv = 1.f / lrun[rr];
    int q = q0 + g*4 + rr;
    #pragma unroll
    for (int df=0; df<4; ++df)
      out[(b*N_ + q)*C_ + h*Dh + df*16 + r] = f2bf(o[df][rr] * inv);
  }
}

// ---------------- host ----------------
extern "C" void kernel_launch(void* const* d_in, const int* in_sizes, int n_in,
                              void* d_out, int out_size, void* d_ws, size_t ws_size,
                              hipStream_t stream)
{
  const float* x      = (const float*)d_in[0];
  const float* W_qkv  = (const float*)d_in[1];
  const float* b_qkv  = (const float*)d_in[2];
  const float* kA     = (const float*)d_in[3];
  const float* kB     = (const float*)d_in[4];
  const float* vA     = (const float*)d_in[5];
  const float* vB     = (const float*)d_in[6];
  const float* W_proj = (const float*)d_in[7];
  const float* b_proj = (const float*)d_in[8];
  float* out = (float*)d_out;

  ushort* ws    = (ushort*)d_ws;
  ushort* xb    = ws;                    // 16,777,216 elems (reused as attn_out later)
  ushort* wqkvb = xb + 16777216;         // 3,145,728
  ushort* kvAb  = wqkvb + 3145728;       // 131,072  ([kA;vA] as 128x1024)
  ushort* kBb   = kvAb + 131072;         // 65,536   (pre-scaled by alpha/r)
  ushort* vBb   = kBb + 65536;           // 65,536
  ushort* wprojb= vBb + 65536;           // 1,048,576
  ushort* tkv   = wprojb + 1048576;      // 2,097,152 ([x@kA^T | x@vA^T], 16384x128)
  ushort* qbuf  = tkv + 2097152;         // 16,777,216 each
  ushort* kbuf  = qbuf + 16777216;
  ushort* vbuf  = kbuf + 16777216;
  ushort* attn  = xb;                    // alias: xb dead after qkv GEMM

  const float ls = 1.0f / 64.0f;         // LORA_ALPHA / LORA_RANK

  auto cast = [&](const float* src, ushort* dst, int n, float scale) {
    int n4 = n >> 2;
    int blocks = (n4 + 255) / 256; if (blocks > 4096) blocks = 4096;
    cast_bf16_k<<<dim3(blocks), dim3(256), 0, stream>>>(src, dst, n4, scale);
  };
  cast(x,      xb,           16777216, 1.f);
  cast(W_qkv,  wqkvb,        3145728,  1.f);
  cast(kA,     kvAb,         65536,    1.f);
  cast(vA,     kvAb + 65536, 65536,    1.f);
  cast(kB,     kBb,          65536,    ls);
  cast(vB,     vBb,          65536,    ls);
  cast(W_proj, wprojb,       1048576,  1.f);

  // LoRA stage-1: tkv = xb @ [kA;vA]^T  (16384 x 128, K=1024)
  gemm128<0><<<dim3(128, 1), dim3(256), 0, stream>>>(
      xb, 1024, kvAb, 1024, nullptr, nullptr, nullptr, nullptr,
      tkv, nullptr, nullptr, nullptr, 0);

  // qkv GEMM + bias + fused LoRA tail, scatter to q/k/v (B,H,N,D); q pre-scaled
  gemm128<1><<<dim3(128, 24), dim3(256), 0, stream>>>(
      xb, 1024, wqkvb, 1024, b_qkv, tkv, kBb, vBb,
      qbuf, kbuf, vbuf, nullptr, 0);

  // flash attention -> attn (B,N,C) bf16
  flash_attn<<<dim3(B_*H_*(N_/64)), dim3(256), 0, stream>>>(qbuf, kbuf, vbuf, attn);

  // final projection -> fp32 d_out
  gemm128<2><<<dim3(128, 8), dim3(256), 0, stream>>>(
      attn, 1024, wprojb, 1024, b_proj, nullptr, nullptr, nullptr,
      nullptr, nullptr, nullptr, out, 1024);
}

// Round 2
// 469.574 us; speedup vs baseline: 1.1640x; 1.1640x over previous
//
#include <hip/hip_runtime.h>
#include <hip/hip_bf16.h>
#include <stdint.h>

#define B_  16
#define N_  1024
#define C_  1024
#define H_  16
#define Dh  64
#define M_  (B_*N_)
#define QSCALE (0.125f * 1.44269504f)   // softmax scale * log2(e), folded into q

typedef __attribute__((ext_vector_type(8))) short short8;
typedef __attribute__((ext_vector_type(4))) float f32x4;

__device__ __forceinline__ ushort f2bf(float f) {
  union { float f; uint32_t u; } v; v.f = f;
  uint32_t u = v.u;
  u += 0x7fffu + ((u >> 16) & 1u);      // RNE
  return (ushort)(u >> 16);
}

__device__ __forceinline__ float exp2fast(float x) {
#if __has_builtin(__builtin_amdgcn_exp2f)
  return __builtin_amdgcn_exp2f(x);
#else
  return exp2f(x);
#endif
}

__device__ __forceinline__ void gload_lds16(const ushort* g, ushort* l) {
  __builtin_amdgcn_global_load_lds((const __attribute__((address_space(1))) void*)g,
                                   (__attribute__((address_space(3))) void*)l, 16, 0, 0);
}

// ---------------- cast fp32 -> bf16 (vectorized, optional scale) ----------------
__global__ void cast_bf16_k(const float* __restrict__ src, ushort* __restrict__ dst,
                            int n4, float scale) {
  int i = blockIdx.x * blockDim.x + threadIdx.x;
  int stride = gridDim.x * blockDim.x;
  for (; i < n4; i += stride) {
    float4 v = reinterpret_cast<const float4*>(src)[i];
    ushort4 o;
    o.x = f2bf(v.x * scale);
    o.y = f2bf(v.y * scale);
    o.z = f2bf(v.z * scale);
    o.w = f2bf(v.w * scale);
    reinterpret_cast<ushort4*>(dst)[i] = o;
  }
}

// ---------------- 128x128 bf16 GEMM, B^T layout (Bm[n][k]), BK=32 ----------------
// MODE 0: out = A@B^T            -> oq as bf16 [M][128]   (lora stage-1)
// MODE 1: qkv (q,k cols) + bias + lora-k tail -> scatter q/k bf16 (B,H,N,D); q scaled
// MODE 2: out = A@B^T + bias     -> of fp32 [M][ldo]      (final proj)
// MODE 3: vT = Wv@x^T + bias + lora-v tail (swapped operands) -> ov bf16 (B,H,D,N)
template<int MODE>
__global__ __launch_bounds__(256)
void gemm128(const ushort* __restrict__ A, int lda,
             const ushort* __restrict__ Bm, int ldb,
             const float* __restrict__ bias,
             const ushort* __restrict__ A2,
             const ushort* __restrict__ B2k, const ushort* __restrict__ B2v,
             ushort* __restrict__ oq, ushort* __restrict__ ok, ushort* __restrict__ ov,
             float* __restrict__ of, int ldo)
{
  __shared__ ushort sA[2][128*32];
  __shared__ ushort sB[2][128*32];
  const int t = threadIdx.x;
  const int lane = t & 63, w = t >> 6;
  const int wr = w >> 1, wc = w & 1;
  const int r = lane & 15, g = lane >> 4;
  const int m0 = blockIdx.x * 128, n0 = blockIdx.y * 128;

  const int s = n0 >> 10;
  int nt = 32;
  const ushort* A2b = nullptr; const ushort* B2 = nullptr; int n0loc = 0;
  if (MODE == 1 && s == 1) {
    nt = 34;                              // +2 tiles of K=32 for the LoRA rank-64 tail
    A2b = A2;                             // tkv k-cols 0..63
    B2 = B2k;
    n0loc = n0 - 1024;
  }
  if (MODE == 3) nt = 34;

  auto stage = [&](int buf, int tt) {
    const ushort* Ab; const ushort* Bb; int ldaT, ldbT;
    if (tt < 32) { Ab = A + m0*lda + tt*32; ldaT = lda; Bb = Bm + n0*ldb + tt*32; ldbT = ldb; }
    else if (MODE == 3) {
      // A-tail: vB rows (c, ld 64); B-tail: tkv v-cols (m rows, ld 128, offset 64)
      Ab = A2 + m0*64 + (tt-32)*32; ldaT = 64;
      Bb = B2k + n0*128 + (tt-32)*32; ldbT = 128;
    } else {
      Ab = A2b + m0*128 + (tt-32)*32; ldaT = 128;
      Bb = B2 + n0loc*64 + (tt-32)*32; ldbT = 64;
    }
    #pragma unroll
    for (int i = 0; i < 2; ++i) {
      int c = i*256 + t;                  // 512 chunks of 16B per tile
      gload_lds16(Ab + (c>>2)*ldaT + (c&3)*8, &sA[buf][c*8]);
      gload_lds16(Bb + (c>>2)*ldbT + (c&3)*8, &sB[buf][c*8]);
    }
  };

  f32x4 acc[4][4];
  #pragma unroll
  for (int i=0;i<4;++i)
    #pragma unroll
    for (int j=0;j<4;++j) acc[i][j] = (f32x4){0.f,0.f,0.f,0.f};

  stage(0, 0);
  __syncthreads();
  for (int tt = 0; tt < nt; ++tt) {
    int cur = tt & 1;
    if (tt + 1 < nt) stage(cur ^ 1, tt + 1);
    short8 af[4], bfr[4];
    #pragma unroll
    for (int i=0;i<4;++i) af[i]  = *(const short8*)&sA[cur][(wr*64 + i*16 + r)*32 + g*8];
    #pragma unroll
    for (int j=0;j<4;++j) bfr[j] = *(const short8*)&sB[cur][(wc*64 + j*16 + r)*32 + g*8];
    #pragma unroll
    for (int i=0;i<4;++i)
      #pragma unroll
      for (int j=0;j<4;++j)
        acc[i][j] = __builtin_amdgcn_mfma_f32_16x16x32_bf16(af[i], bfr[j], acc[i][j], 0,0,0);
    __syncthreads();
  }

  #pragma unroll
  for (int i=0;i<4;++i) {
    #pragma unroll
    for (int j=0;j<4;++j) {
      #pragma unroll
      for (int rr=0;rr<4;++rr) {
        int m = m0 + wr*64 + i*16 + g*4 + rr;
        int n = n0 + wc*64 + j*16 + r;
        float v = acc[i][j][rr];
        if (MODE == 0) {
          oq[m*128 + n] = f2bf(v);
        } else if (MODE == 1) {
          v += bias[n];
          int b = m >> 10, nq = m & 1023;
          int c = n & 1023, h = c >> 6, d = c & 63;
          int idx = ((b*H_ + h)*N_ + nq)*Dh + d;
          if (s == 0)      oq[idx] = f2bf(v * QSCALE);
          else             ok[idx] = f2bf(v);
        } else if (MODE == 3) {
          // row m = channel c of V; col n = token index
          v += bias[m];
          int h = m >> 6, d = m & 63;
          int b = n >> 10, nq = n & 1023;
          ov[((b*H_ + h)*Dh + d)*N_ + nq] = f2bf(v);
        } else {
          of[m*ldo + n] = v + bias[n];
        }
      }
    }
  }
}

// ---------------- flash attention: 4 waves x 16 q-rows, KV tiles of 64 ----------------
// V is pre-transposed: vb layout (B,H,D,N)
__global__ __launch_bounds__(256)
void flash_attn(const ushort* __restrict__ qb, const ushort* __restrict__ kb,
                const ushort* __restrict__ vb, ushort* __restrict__ out)
{
  __shared__ ushort Kt[64*64];     // row-major [k][d], 16B-chunk XOR-swizzled per row
  __shared__ ushort Vt[64*64];     // row-major [d][k], 16B-chunk XOR-swizzled per row
  __shared__ ushort Pl[4][16*72];  // per-wave P, stride 72
  const int t = threadIdx.x, w = t >> 6, lane = t & 63;
  const int r = lane & 15, g = lane >> 4;
  const int bh = blockIdx.x >> 4, qt = blockIdx.x & 15;
  const int b = bh >> 4, h = bh & 15;
  const ushort* Q  = qb + bh * (N_*Dh);
  const ushort* K  = kb + bh * (N_*Dh);
  const ushort* VT = vb + bh * (Dh*N_);
  const int q0 = qt*64 + w*16;

  short8 qf[2];
  #pragma unroll
  for (int hh=0; hh<2; ++hh) qf[hh] = *(const short8*)&Q[(q0 + r)*Dh + hh*32 + g*8];

  f32x4 o[4];
  #pragma unroll
  for (int i=0;i<4;++i) o[i] = (f32x4){0.f,0.f,0.f,0.f};
  float mrun[4] = {-1e30f,-1e30f,-1e30f,-1e30f};
  float lrun[4] = {0.f,0.f,0.f,0.f};

  for (int kt = 0; kt < 16; ++kt) {
    // stage K and V^T tiles, source-preswizzled so LDS stays linear for global_load_lds
    #pragma unroll
    for (int i=0;i<2;++i) {
      int ch = i*256 + t;
      int row = ch >> 3, sc = ch & 7;
      int c = sc ^ (row & 7);
      gload_lds16(&K[(kt*64 + row)*Dh + c*8], &Kt[ch*8]);
      gload_lds16(&VT[row*N_ + kt*64 + c*8], &Vt[ch*8]);
    }
    __syncthreads();

    // S = Q @ K^T (log2-domain, scale pre-folded into q)
    f32x4 sfr[4];
    #pragma unroll
    for (int kf=0; kf<4; ++kf) {
      sfr[kf] = (f32x4){0.f,0.f,0.f,0.f};
      int krow = kf*16 + r;
      #pragma unroll
      for (int hh=0; hh<2; ++hh) {
        int slot = (hh*4 + g) ^ (krow & 7);
        short8 kfrag = *(const short8*)&Kt[krow*64 + slot*8];
        sfr[kf] = __builtin_amdgcn_mfma_f32_16x16x32_bf16(qf[hh], kfrag, sfr[kf], 0,0,0);
      }
    }

    // online softmax (wave-parallel: shfl_xor over the 16 lanes sharing rows)
    float fac[4], psum[4];
    #pragma unroll
    for (int rr=0; rr<4; ++rr) {
      float mx = fmaxf(fmaxf(sfr[0][rr], sfr[1][rr]), fmaxf(sfr[2][rr], sfr[3][rr]));
      #pragma unroll
      for (int d = 1; d < 16; d <<= 1) mx = fmaxf(mx, __shfl_xor(mx, d));
      float nm = fmaxf(mrun[rr], mx);
      fac[rr] = exp2fast(mrun[rr] - nm);
      mrun[rr] = nm;
      float ps = 0.f;
      #pragma unroll
      for (int kf=0; kf<4; ++kf) {
        float p = exp2fast(sfr[kf][rr] - nm);
        Pl[w][(g*4 + rr)*72 + kf*16 + r] = f2bf(p);
        ps += p;
      }
      #pragma unroll
      for (int d = 1; d < 16; d <<= 1) ps += __shfl_xor(ps, d);
      psum[rr] = ps;
    }
    #pragma unroll
    for (int rr=0; rr<4; ++rr) lrun[rr] = lrun[rr]*fac[rr] + psum[rr];
    #pragma unroll
    for (int df=0; df<4; ++df)
      #pragma unroll
      for (int rr=0; rr<4; ++rr) o[df][rr] *= fac[rr];

    // O += P @ V   (P via per-wave LDS; V^T fragments direct from swizzled Vt)
    short8 pa[2];
    #pragma unroll
    for (int hh=0; hh<2; ++hh) pa[hh] = *(const short8*)&Pl[w][r*72 + hh*32 + g*8];
    #pragma unroll
    for (int df=0; df<4; ++df) {
      int vrow = df*16 + r;
      #pragma unroll
      for (int hh=0; hh<2; ++hh) {
        int slot = (hh*4 + g) ^ (vrow & 7);
        short8 vfrag = *(const short8*)&Vt[vrow*64 + slot*8];
        o[df] = __builtin_amdgcn_mfma_f32_16x16x32_bf16(pa[hh], vfrag, o[df], 0,0,0);
      }
    }
    __syncthreads();
  }

  #pragma unroll
  for (int rr=0; rr<4; ++rr) {
    float inv = 1.f / lrun[rr];
    int q = q0 + g*4 + rr;
    #pragma unroll
    for (int df=0; df<4; ++df)
      out[(b*N_ + q)*C_ + h*Dh + df*16 + r] = f2bf(o[df][rr] * inv);
  }
}

// ---------------- host ----------------
extern "C" void kernel_launch(void* const* d_in, const int* in_sizes, int n_in,
                              void* d_out, int out_size, void* d_ws, size_t ws_size,
                              hipStream_t stream)
{
  const float* x      = (const float*)d_in[0];
  const float* W_qkv  = (const float*)d_in[1];
  const float* b_qkv  = (const float*)d_in[2];
  const float* kA     = (const float*)d_in[3];
  const float* kB     = (const float*)d_in[4];
  const float* vA     = (const float*)d_in[5];
  const float* vB     = (const float*)d_in[6];
  const float* W_proj = (const float*)d_in[7];
  const float* b_proj = (const float*)d_in[8];
  float* out = (float*)d_out;

  ushort* ws    = (ushort*)d_ws;
  ushort* xb    = ws;                    // 16,777,216 elems (reused as attn_out later)
  ushort* wqkvb = xb + 16777216;         // 3,145,728
  ushort* kvAb  = wqkvb + 3145728;       // 131,072  ([kA;vA] as 128x1024)
  ushort* kBb   = kvAb + 131072;         // 65,536   (pre-scaled by alpha/r)
  ushort* vBb   = kBb + 65536;           // 65,536   (pre-scaled by alpha/r)
  ushort* wprojb= vBb + 65536;           // 1,048,576
  ushort* tkv   = wprojb + 1048576;      // 2,097,152 ([x@kA^T | x@vA^T], 16384x128)
  ushort* qbuf  = tkv + 2097152;         // 16,777,216 each
  ushort* kbuf  = qbuf + 16777216;
  ushort* vbuf  = kbuf + 16777216;       // V^T layout (B,H,D,N)
  ushort* attn  = xb;                    // alias: xb dead after qkv/vT GEMMs

  const float ls = 1.0f / 64.0f;         // LORA_ALPHA / LORA_RANK

  auto cast = [&](const float* src, ushort* dst, int n, float scale) {
    int n4 = n >> 2;
    int blocks = (n4 + 255) / 256; if (blocks > 4096) blocks = 4096;
    cast_bf16_k<<<dim3(blocks), dim3(256), 0, stream>>>(src, dst, n4, scale);
  };
  cast(x,      xb,           16777216, 1.f);
  cast(W_qkv,  wqkvb,        3145728,  1.f);
  cast(kA,     kvAb,         65536,    1.f);
  cast(vA,     kvAb + 65536, 65536,    1.f);
  cast(kB,     kBb,          65536,    ls);
  cast(vB,     vBb,          65536,    ls);
  cast(W_proj, wprojb,       1048576,  1.f);

  // LoRA stage-1: tkv = xb @ [kA;vA]^T  (16384 x 128, K=1024)
  gemm128<0><<<dim3(128, 1), dim3(256), 0, stream>>>(
      xb, 1024, kvAb, 1024, nullptr, nullptr, nullptr, nullptr,
      tkv, nullptr, nullptr, nullptr, 0);

  // q,k GEMM + bias + fused LoRA-k tail, scatter to q/k (B,H,N,D); q pre-scaled
  gemm128<1><<<dim3(128, 16), dim3(256), 0, stream>>>(
      xb, 1024, wqkvb, 1024, b_qkv, tkv, kBb, nullptr,
      qbuf, kbuf, nullptr, nullptr, 0);

  // vT GEMM (swapped operands) + bias + fused LoRA-v tail -> vbuf (B,H,D,N)
  gemm128<3><<<dim3(8, 128), dim3(256), 0, stream>>>(
      wqkvb + 2048*1024, 1024, xb, 1024, b_qkv + 2048, vBb, tkv + 64, nullptr,
      nullptr, nullptr, vbuf, nullptr, 0);

  // flash attention -> attn (B,N,C) bf16
  flash_attn<<<dim3(B_*H_*(N_/64)), dim3(256), 0, stream>>>(qbuf, kbuf, vbuf, attn);

  // final projection -> fp32 d_out
  gemm128<2><<<dim3(128, 8), dim3(256), 0, stream>>>(
      attn, 1024, wprojb, 1024, b_proj, nullptr, nullptr, nullptr,
      nullptr, nullptr, nullptr, out, 1024);
}

// Round 3
// 435.344 us; speedup vs baseline: 1.2555x; 1.0786x over previous
//
#include <hip/hip_runtime.h>
#include <hip/hip_bf16.h>
#include <stdint.h>

#define B_  16
#define N_  1024
#define C_  1024
#define H_  16
#define Dh  64
#define M_  (B_*N_)
#define QSCALE (0.125f * 1.44269504f)   // softmax scale * log2(e), folded into q

typedef __attribute__((ext_vector_type(8))) short short8;
typedef __attribute__((ext_vector_type(4))) float f32x4;

__device__ __forceinline__ ushort f2bf(float f) {
  union { float f; uint32_t u; } v; v.f = f;
  uint32_t u = v.u;
  u += 0x7fffu + ((u >> 16) & 1u);      // RNE
  return (ushort)(u >> 16);
}

__device__ __forceinline__ ushort f2bf_fast(float f) {   // round-half-up, 2 ops
  union { float f; uint32_t u; } v; v.f = f;
  return (ushort)((v.u + 0x8000u) >> 16);
}

__device__ __forceinline__ float exp2fast(float x) {
#if __has_builtin(__builtin_amdgcn_exp2f)
  return __builtin_amdgcn_exp2f(x);
#else
  return exp2f(x);
#endif
}

__device__ __forceinline__ void gload_lds16(const ushort* g, ushort* l) {
  __builtin_amdgcn_global_load_lds((const __attribute__((address_space(1))) void*)g,
                                   (__attribute__((address_space(3))) void*)l, 16, 0, 0);
}

// ---------------- cast fp32 -> bf16 (vectorized, optional scale) ----------------
__global__ void cast_bf16_k(const float* __restrict__ src, ushort* __restrict__ dst,
                            int n4, float scale) {
  int i = blockIdx.x * blockDim.x + threadIdx.x;
  int stride = gridDim.x * blockDim.x;
  for (; i < n4; i += stride) {
    float4 v = reinterpret_cast<const float4*>(src)[i];
    ushort4 o;
    o.x = f2bf(v.x * scale);
    o.y = f2bf(v.y * scale);
    o.z = f2bf(v.z * scale);
    o.w = f2bf(v.w * scale);
    reinterpret_cast<ushort4*>(dst)[i] = o;
  }
}

// ---------------- 128x128 bf16 GEMM, B^T layout (Bm[n][k]), BK=32 ----------------
// MODE 0: out = A@B^T            -> oq as bf16 [M][128]   (lora stage-1)
// MODE 1: qkv (q,k cols) + bias + lora-k tail -> scatter q/k bf16 (B,H,N,D); q scaled
// MODE 2: out = A@B^T + bias     -> of fp32 [M][ldo]      (final proj)
// MODE 3: vT = Wv@x^T + bias + lora-v tail (swapped operands) -> ov bf16 (B,H,D,N)
template<int MODE>
__global__ __launch_bounds__(256)
void gemm128(const ushort* __restrict__ A, int lda,
             const ushort* __restrict__ Bm, int ldb,
             const float* __restrict__ bias,
             const ushort* __restrict__ A2,
             const ushort* __restrict__ B2k, const ushort* __restrict__ B2v,
             ushort* __restrict__ oq, ushort* __restrict__ ok, ushort* __restrict__ ov,
             float* __restrict__ of, int ldo)
{
  __shared__ ushort sA[2][128*32];
  __shared__ ushort sB[2][128*32];
  const int t = threadIdx.x;
  const int lane = t & 63, w = t >> 6;
  const int wr = w >> 1, wc = w & 1;
  const int r = lane & 15, g = lane >> 4;
  const int m0 = blockIdx.x * 128, n0 = blockIdx.y * 128;

  const int s = n0 >> 10;
  int nt = 32;
  const ushort* A2b = nullptr; const ushort* B2 = nullptr; int n0loc = 0;
  if (MODE == 1 && s == 1) {
    nt = 34;                              // +2 tiles of K=32 for the LoRA rank-64 tail
    A2b = A2;                             // tkv k-cols 0..63
    B2 = B2k;
    n0loc = n0 - 1024;
  }
  if (MODE == 3) nt = 34;

  auto stage = [&](int buf, int tt) {
    const ushort* Ab; const ushort* Bb; int ldaT, ldbT;
    if (tt < 32) { Ab = A + m0*lda + tt*32; ldaT = lda; Bb = Bm + n0*ldb + tt*32; ldbT = ldb; }
    else if (MODE == 3) {
      // A-tail: vB rows (c, ld 64); B-tail: tkv v-cols (m rows, ld 128, offset 64)
      Ab = A2 + m0*64 + (tt-32)*32; ldaT = 64;
      Bb = B2k + n0*128 + (tt-32)*32; ldbT = 128;
    } else {
      Ab = A2b + m0*128 + (tt-32)*32; ldaT = 128;
      Bb = B2 + n0loc*64 + (tt-32)*32; ldbT = 64;
    }
    #pragma unroll
    for (int i = 0; i < 2; ++i) {
      int c = i*256 + t;                  // 512 chunks of 16B per tile
      gload_lds16(Ab + (c>>2)*ldaT + (c&3)*8, &sA[buf][c*8]);
      gload_lds16(Bb + (c>>2)*ldbT + (c&3)*8, &sB[buf][c*8]);
    }
  };

  f32x4 acc[4][4];
  #pragma unroll
  for (int i=0;i<4;++i)
    #pragma unroll
    for (int j=0;j<4;++j) acc[i][j] = (f32x4){0.f,0.f,0.f,0.f};

  stage(0, 0);
  __syncthreads();
  for (int tt = 0; tt < nt; ++tt) {
    int cur = tt & 1;
    if (tt + 1 < nt) stage(cur ^ 1, tt + 1);
    short8 af[4], bfr[4];
    #pragma unroll
    for (int i=0;i<4;++i) af[i]  = *(const short8*)&sA[cur][(wr*64 + i*16 + r)*32 + g*8];
    #pragma unroll
    for (int j=0;j<4;++j) bfr[j] = *(const short8*)&sB[cur][(wc*64 + j*16 + r)*32 + g*8];
    #pragma unroll
    for (int i=0;i<4;++i)
      #pragma unroll
      for (int j=0;j<4;++j)
        acc[i][j] = __builtin_amdgcn_mfma_f32_16x16x32_bf16(af[i], bfr[j], acc[i][j], 0,0,0);
    __syncthreads();
  }

  #pragma unroll
  for (int i=0;i<4;++i) {
    #pragma unroll
    for (int j=0;j<4;++j) {
      #pragma unroll
      for (int rr=0;rr<4;++rr) {
        int m = m0 + wr*64 + i*16 + g*4 + rr;
        int n = n0 + wc*64 + j*16 + r;
        float v = acc[i][j][rr];
        if (MODE == 0) {
          oq[m*128 + n] = f2bf(v);
        } else if (MODE == 1) {
          v += bias[n];
          int b = m >> 10, nq = m & 1023;
          int c = n & 1023, h = c >> 6, d = c & 63;
          int idx = ((b*H_ + h)*N_ + nq)*Dh + d;
          if (s == 0)      oq[idx] = f2bf(v * QSCALE);
          else             ok[idx] = f2bf(v);
        } else if (MODE == 3) {
          // row m = channel c of V; col n = token index
          v += bias[m];
          int h = m >> 6, d = m & 63;
          int b = n >> 10, nq = n & 1023;
          ov[((b*H_ + h)*Dh + d)*N_ + nq] = f2bf(v);
        } else {
          of[m*ldo + n] = v + bias[n];
        }
      }
    }
  }
}

// ---------------- flash attention: 4 waves x 16 q-rows, KV tiles of 64 ----------------
// V is pre-transposed: vb layout (B,H,D,N). Softmax denominator via ones-column MFMA;
// defer-max (THR=8 in log2 domain) skips the O/l rescale on most tiles.
__global__ __launch_bounds__(256)
void flash_attn(const ushort* __restrict__ qb, const ushort* __restrict__ kb,
                const ushort* __restrict__ vb, ushort* __restrict__ out)
{
  __shared__ ushort Kt[64*64];     // row-major [k][d], 16B-chunk XOR-swizzled per row
  __shared__ ushort Vt[64*64];     // row-major [d][k], 16B-chunk XOR-swizzled per row
  __shared__ ushort Pl[4][16*72];  // per-wave P, stride 72
  const int t = threadIdx.x, w = t >> 6, lane = t & 63;
  const int r = lane & 15, g = lane >> 4;
  const int bh = blockIdx.x >> 4, qt = blockIdx.x & 15;
  const int b = bh >> 4, h = bh & 15;
  const ushort* Q  = qb + bh * (N_*Dh);
  const ushort* K  = kb + bh * (N_*Dh);
  const ushort* VT = vb + bh * (Dh*N_);
  const int q0 = qt*64 + w*16;

  short8 qf[2];
  #pragma unroll
  for (int hh=0; hh<2; ++hh) qf[hh] = *(const short8*)&Q[(q0 + r)*Dh + hh*32 + g*8];

  short8 ones;
  #pragma unroll
  for (int j=0;j<8;++j) ones[j] = (short)0x3F80;   // bf16 1.0

  f32x4 o[4];
  #pragma unroll
  for (int i=0;i<4;++i) o[i] = (f32x4){0.f,0.f,0.f,0.f};
  f32x4 ol = (f32x4){0.f,0.f,0.f,0.f};             // row-sum (denominator) via MFMA
  float mrun[4] = {-1e30f,-1e30f,-1e30f,-1e30f};

  for (int kt = 0; kt < 16; ++kt) {
    // stage K and V^T tiles, source-preswizzled so LDS stays linear for global_load_lds
    #pragma unroll
    for (int i=0;i<2;++i) {
      int ch = i*256 + t;
      int row = ch >> 3, sc = ch & 7;
      int c = sc ^ (row & 7);
      gload_lds16(&K[(kt*64 + row)*Dh + c*8], &Kt[ch*8]);
      gload_lds16(&VT[row*N_ + kt*64 + c*8], &Vt[ch*8]);
    }
    __syncthreads();

    // S = Q @ K^T (log2-domain, scale pre-folded into q)
    f32x4 sfr[4];
    #pragma unroll
    for (int kf=0; kf<4; ++kf) {
      sfr[kf] = (f32x4){0.f,0.f,0.f,0.f};
      int krow = kf*16 + r;
      #pragma unroll
      for (int hh=0; hh<2; ++hh) {
        int slot = (hh*4 + g) ^ (krow & 7);
        short8 kfrag = *(const short8*)&Kt[krow*64 + slot*8];
        sfr[kf] = __builtin_amdgcn_mfma_f32_16x16x32_bf16(qf[hh], kfrag, sfr[kf], 0,0,0);
      }
    }

    // tile row-max (in-lane over kf, then 16-lane shfl reduce)
    float pmax[4];
    #pragma unroll
    for (int rr=0; rr<4; ++rr) {
      float mx = fmaxf(fmaxf(sfr[0][rr], sfr[1][rr]), fmaxf(sfr[2][rr], sfr[3][rr]));
      #pragma unroll
      for (int d = 1; d < 16; d <<= 1) mx = fmaxf(mx, __shfl_xor(mx, d));
      pmax[rr] = mx;
    }

    // defer-max: only rescale when some row grew by more than 8 (log2 domain)
    bool need = (pmax[0] > mrun[0] + 8.f) | (pmax[1] > mrun[1] + 8.f) |
                (pmax[2] > mrun[2] + 8.f) | (pmax[3] > mrun[3] + 8.f);
    if (__any(need)) {
      #pragma unroll
      for (int rr=0; rr<4; ++rr) {
        float nm = fmaxf(mrun[rr], pmax[rr]);
        float fac = exp2fast(mrun[rr] - nm);
        mrun[rr] = nm;
        ol[rr] *= fac;
        #pragma unroll
        for (int df=0; df<4; ++df) o[df][rr] *= fac;
      }
    }

    // P = exp2(S - m), store bf16 to per-wave LDS
    #pragma unroll
    for (int rr=0; rr<4; ++rr) {
      #pragma unroll
      for (int kf=0; kf<4; ++kf) {
        float p = exp2fast(sfr[kf][rr] - mrun[rr]);
        Pl[w][(g*4 + rr)*72 + kf*16 + r] = f2bf_fast(p);
      }
    }

    // O += P @ V ; l += P @ 1  (V^T fragments direct from swizzled Vt)
    short8 pa[2];
    #pragma unroll
    for (int hh=0; hh<2; ++hh) pa[hh] = *(const short8*)&Pl[w][r*72 + hh*32 + g*8];
    #pragma unroll
    for (int df=0; df<4; ++df) {
      int vrow = df*16 + r;
      #pragma unroll
      for (int hh=0; hh<2; ++hh) {
        int slot = (hh*4 + g) ^ (vrow & 7);
        short8 vfrag = *(const short8*)&Vt[vrow*64 + slot*8];
        o[df] = __builtin_amdgcn_mfma_f32_16x16x32_bf16(pa[hh], vfrag, o[df], 0,0,0);
      }
    }
    ol = __builtin_amdgcn_mfma_f32_16x16x32_bf16(pa[0], ones, ol, 0,0,0);
    ol = __builtin_amdgcn_mfma_f32_16x16x32_bf16(pa[1], ones, ol, 0,0,0);
    __syncthreads();
  }

  #pragma unroll
  for (int rr=0; rr<4; ++rr) {
    float inv = 1.f / ol[rr];          // lane's col r holds its own row's l (replicated)
    int q = q0 + g*4 + rr;
    #pragma unroll
    for (int df=0; df<4; ++df)
      out[(b*N_ + q)*C_ + h*Dh + df*16 + r] = f2bf(o[df][rr] * inv);
  }
}

// ---------------- host ----------------
extern "C" void kernel_launch(void* const* d_in, const int* in_sizes, int n_in,
                              void* d_out, int out_size, void* d_ws, size_t ws_size,
                              hipStream_t stream)
{
  const float* x      = (const float*)d_in[0];
  const float* W_qkv  = (const float*)d_in[1];
  const float* b_qkv  = (const float*)d_in[2];
  const float* kA     = (const float*)d_in[3];
  const float* kB     = (const float*)d_in[4];
  const float* vA     = (const float*)d_in[5];
  const float* vB     = (const float*)d_in[6];
  const float* W_proj = (const float*)d_in[7];
  const float* b_proj = (const float*)d_in[8];
  float* out = (float*)d_out;

  ushort* ws    = (ushort*)d_ws;
  ushort* xb    = ws;                    // 16,777,216 elems (reused as attn_out later)
  ushort* wqkvb = xb + 16777216;         // 3,145,728
  ushort* kvAb  = wqkvb + 3145728;       // 131,072  ([kA;vA] as 128x1024)
  ushort* kBb   = kvAb + 131072;         // 65,536   (pre-scaled by alpha/r)
  ushort* vBb   = kBb + 65536;           // 65,536   (pre-scaled by alpha/r)
  ushort* wprojb= vBb + 65536;           // 1,048,576
  ushort* tkv   = wprojb + 1048576;      // 2,097,152 ([x@kA^T | x@vA^T], 16384x128)
  ushort* qbuf  = tkv + 2097152;         // 16,777,216 each
  ushort* kbuf  = qbuf + 16777216;
  ushort* vbuf  = kbuf + 16777216;       // V^T layout (B,H,D,N)
  ushort* attn  = xb;                    // alias: xb dead after qkv/vT GEMMs

  const float ls = 1.0f / 64.0f;         // LORA_ALPHA / LORA_RANK

  auto cast = [&](const float* src, ushort* dst, int n, float scale) {
    int n4 = n >> 2;
    int blocks = (n4 + 255) / 256; if (blocks > 4096) blocks = 4096;
    cast_bf16_k<<<dim3(blocks), dim3(256), 0, stream>>>(src, dst, n4, scale);
  };
  cast(x,      xb,           16777216, 1.f);
  cast(W_qkv,  wqkvb,        3145728,  1.f);
  cast(kA,     kvAb,         65536,    1.f);
  cast(vA,     kvAb + 65536, 65536,    1.f);
  cast(kB,     kBb,          65536,    ls);
  cast(vB,     vBb,          65536,    ls);
  cast(W_proj, wprojb,       1048576,  1.f);

  // LoRA stage-1: tkv = xb @ [kA;vA]^T  (16384 x 128, K=1024)
  gemm128<0><<<dim3(128, 1), dim3(256), 0, stream>>>(
      xb, 1024, kvAb, 1024, nullptr, nullptr, nullptr, nullptr,
      tkv, nullptr, nullptr, nullptr, 0);

  // q,k GEMM + bias + fused LoRA-k tail, scatter to q/k (B,H,N,D); q pre-scaled
  gemm128<1><<<dim3(128, 16), dim3(256), 0, stream>>>(
      xb, 1024, wqkvb, 1024, b_qkv, tkv, kBb, nullptr,
      qbuf, kbuf, nullptr, nullptr, 0);

  // vT GEMM (swapped operands) + bias + fused LoRA-v tail -> vbuf (B,H,D,N)
  gemm128<3><<<dim3(8, 128), dim3(256), 0, stream>>>(
      wqkvb + 2048*1024, 1024, xb, 1024, b_qkv + 2048, vBb, tkv + 64, nullptr,
      nullptr, nullptr, vbuf, nullptr, 0);

  // flash attention -> attn (B,N,C) bf16
  flash_attn<<<dim3(B_*H_*(N_/64)), dim3(256), 0, stream>>>(qbuf, kbuf, vbuf, attn);

  // final projection -> fp32 d_out
  gemm128<2><<<dim3(128, 8), dim3(256), 0, stream>>>(
      attn, 1024, wprojb, 1024, b_proj, nullptr, nullptr, nullptr,
      nullptr, nullptr, nullptr, out, 1024);
}

// Round 5
// 391.439 us; speedup vs baseline: 1.3963x; 1.1122x over previous
//
#include <hip/hip_runtime.h>
#include <hip/hip_bf16.h>
#include <stdint.h>

#define B_  16
#define N_  1024
#define C_  1024
#define H_  16
#define Dh  64
#define M_  (B_*N_)
#define QSCALE (0.125f * 1.44269504f)   // softmax scale * log2(e), folded into q

typedef __attribute__((ext_vector_type(8)))  short short8;
typedef __attribute__((ext_vector_type(4)))  float f32x4;
typedef __attribute__((ext_vector_type(16))) float f32x16;

__device__ __forceinline__ ushort f2bf(float f) {
  union { float f; uint32_t u; } v; v.f = f;
  uint32_t u = v.u;
  u += 0x7fffu + ((u >> 16) & 1u);      // RNE
  return (ushort)(u >> 16);
}

__device__ __forceinline__ ushort f2bf_fast(float f) {   // round-half-up, 2 ops
  union { float f; uint32_t u; } v; v.f = f;
  return (ushort)((v.u + 0x8000u) >> 16);
}

__device__ __forceinline__ float exp2fast(float x) {
#if __has_builtin(__builtin_amdgcn_exp2f)
  return __builtin_amdgcn_exp2f(x);
#else
  return exp2f(x);
#endif
}

__device__ __forceinline__ void gload_lds16(const ushort* g, ushort* l) {
  __builtin_amdgcn_global_load_lds((const __attribute__((address_space(1))) void*)g,
                                   (__attribute__((address_space(3))) void*)l, 16, 0, 0);
}

// ---------------- cast fp32 -> bf16 (vectorized, optional scale) ----------------
__global__ void cast_bf16_k(const float* __restrict__ src, ushort* __restrict__ dst,
                            int n4, float scale) {
  int i = blockIdx.x * blockDim.x + threadIdx.x;
  int stride = gridDim.x * blockDim.x;
  for (; i < n4; i += stride) {
    float4 v = reinterpret_cast<const float4*>(src)[i];
    ushort4 o;
    o.x = f2bf(v.x * scale);
    o.y = f2bf(v.y * scale);
    o.z = f2bf(v.z * scale);
    o.w = f2bf(v.w * scale);
    reinterpret_cast<ushort4*>(dst)[i] = o;
  }
}

// ---------------- 128x128 bf16 GEMM, B^T layout (Bm[n][k]), BK=32 ----------------
// MODE 0: out = A@B^T            -> oq as bf16 [M][128]   (lora stage-1)
// MODE 1: qkv (q,k cols) + bias + lora-k tail -> scatter q/k bf16 (B,H,N,D); q scaled
// MODE 2: out = A@B^T + bias     -> of fp32 [M][ldo]      (final proj)
// MODE 3: vT = Wv@x^T + bias + lora-v tail (swapped operands) -> ov bf16 (B,H,D,N)
template<int MODE>
__global__ __launch_bounds__(256)
void gemm128(const ushort* __restrict__ A, int lda,
             const ushort* __restrict__ Bm, int ldb,
             const float* __restrict__ bias,
             const ushort* __restrict__ A2,
             const ushort* __restrict__ B2k, const ushort* __restrict__ B2v,
             ushort* __restrict__ oq, ushort* __restrict__ ok, ushort* __restrict__ ov,
             float* __restrict__ of, int ldo)
{
  __shared__ ushort sA[2][128*32];
  __shared__ ushort sB[2][128*32];
  const int t = threadIdx.x;
  const int lane = t & 63, w = t >> 6;
  const int wr = w >> 1, wc = w & 1;
  const int r = lane & 15, g = lane >> 4;
  const int m0 = blockIdx.x * 128, n0 = blockIdx.y * 128;

  const int s = n0 >> 10;
  int nt = 32;
  const ushort* A2b = nullptr; const ushort* B2 = nullptr; int n0loc = 0;
  if (MODE == 1 && s == 1) {
    nt = 34;                              // +2 tiles of K=32 for the LoRA rank-64 tail
    A2b = A2;                             // tkv k-cols 0..63
    B2 = B2k;
    n0loc = n0 - 1024;
  }
  if (MODE == 3) nt = 34;

  auto stage = [&](int buf, int tt) {
    const ushort* Ab; const ushort* Bb; int ldaT, ldbT;
    if (tt < 32) { Ab = A + m0*lda + tt*32; ldaT = lda; Bb = Bm + n0*ldb + tt*32; ldbT = ldb; }
    else if (MODE == 3) {
      Ab = A2 + m0*64 + (tt-32)*32; ldaT = 64;
      Bb = B2k + n0*128 + (tt-32)*32; ldbT = 128;
    } else {
      Ab = A2b + m0*128 + (tt-32)*32; ldaT = 128;
      Bb = B2 + n0loc*64 + (tt-32)*32; ldbT = 64;
    }
    #pragma unroll
    for (int i = 0; i < 2; ++i) {
      int c = i*256 + t;                  // 512 chunks of 16B per tile
      gload_lds16(Ab + (c>>2)*ldaT + (c&3)*8, &sA[buf][c*8]);
      gload_lds16(Bb + (c>>2)*ldbT + (c&3)*8, &sB[buf][c*8]);
    }
  };

  f32x4 acc[4][4];
  #pragma unroll
  for (int i=0;i<4;++i)
    #pragma unroll
    for (int j=0;j<4;++j) acc[i][j] = (f32x4){0.f,0.f,0.f,0.f};

  stage(0, 0);
  __syncthreads();
  for (int tt = 0; tt < nt; ++tt) {
    int cur = tt & 1;
    if (tt + 1 < nt) stage(cur ^ 1, tt + 1);
    short8 af[4], bfr[4];
    #pragma unroll
    for (int i=0;i<4;++i) af[i]  = *(const short8*)&sA[cur][(wr*64 + i*16 + r)*32 + g*8];
    #pragma unroll
    for (int j=0;j<4;++j) bfr[j] = *(const short8*)&sB[cur][(wc*64 + j*16 + r)*32 + g*8];
    #pragma unroll
    for (int i=0;i<4;++i)
      #pragma unroll
      for (int j=0;j<4;++j)
        acc[i][j] = __builtin_amdgcn_mfma_f32_16x16x32_bf16(af[i], bfr[j], acc[i][j], 0,0,0);
    __syncthreads();
  }

  #pragma unroll
  for (int i=0;i<4;++i) {
    #pragma unroll
    for (int j=0;j<4;++j) {
      #pragma unroll
      for (int rr=0;rr<4;++rr) {
        int m = m0 + wr*64 + i*16 + g*4 + rr;
        int n = n0 + wc*64 + j*16 + r;
        float v = acc[i][j][rr];
        if (MODE == 0) {
          oq[m*128 + n] = f2bf(v);
        } else if (MODE == 1) {
          v += bias[n];
          int b = m >> 10, nq = m & 1023;
          int c = n & 1023, h = c >> 6, d = c & 63;
          int idx = ((b*H_ + h)*N_ + nq)*Dh + d;
          if (s == 0)      oq[idx] = f2bf(v * QSCALE);
          else             ok[idx] = f2bf(v);
        } else if (MODE == 3) {
          v += bias[m];
          int h = m >> 6, d = m & 63;
          int b = n >> 10, nq = n & 1023;
          ov[((b*H_ + h)*Dh + d)*N_ + nq] = f2bf(v);
        } else {
          of[m*ldo + n] = v + bias[n];
        }
      }
    }
  }
}

// ---------------- flash attention: 8 warps x 32 q-rows, 32x32 MFMA, KV tiles of 64 ----
// Swapped QK^T (S^T = K x Q^T) keeps each lane's P-row in registers; softmax fully
// in-register; P repacked to PV A-operand via in-lane bf16 pack + __shfl_xor(32)
// partner exchange (safe primitives only). V pre-transposed in global (B,H,D,N).
// l via ones-column MFMA (rows align with O).
__global__ __launch_bounds__(512)
void flash_attn32(const ushort* __restrict__ qb, const ushort* __restrict__ kb,
                  const ushort* __restrict__ vb, ushort* __restrict__ out)
{
  __shared__ ushort Kt[2][64*64];   // [k][d], 16B-chunk XOR-swizzled per row
  __shared__ ushort Vt[2][64*64];   // [d][k], 16B-chunk XOR-swizzled per row
  const int t = threadIdx.x, w = t >> 6, lane = t & 63;
  const int ql = lane & 31, hi = lane >> 5;

  // XCD-chunked swizzle: the 4 q-blocks sharing one (b,h)'s K/V land on one XCD
  int bid = (blockIdx.x & 7) * 128 + (blockIdx.x >> 3);
  const int bh = bid >> 2, qt = bid & 3;
  const int b = bh >> 4, h = bh & 15;
  const ushort* Q  = qb + bh * (N_*Dh);
  const ushort* K  = kb + bh * (N_*Dh);
  const ushort* VT = vb + bh * (Dh*N_);
  const int q0 = qt*256 + w*32;

  // Q^T B-frags: lane holds col q=ql, contraction d = ds*16 + hi*8 + j
  short8 qf[4];
  #pragma unroll
  for (int ds=0; ds<4; ++ds)
    qf[ds] = *(const short8*)&Q[(q0 + ql)*Dh + ds*16 + hi*8];

  short8 ones;
  #pragma unroll
  for (int j=0;j<8;++j) ones[j] = (short)0x3F80;   // bf16 1.0

  f32x16 o0, o1, lacc;
  #pragma unroll
  for (int r=0;r<16;++r) { o0[r]=0.f; o1[r]=0.f; lacc[r]=0.f; }
  float m = -1e30f;                 // per-lane running max (lane's q row = ql)

  auto stage = [&](int buf, int kt) {
    int row = t >> 3, sc = t & 7;
    int c = sc ^ (row & 7);
    gload_lds16(&K[(kt*64 + row)*Dh + c*8], &Kt[buf][t*8]);
    gload_lds16(&VT[row*N_ + kt*64 + c*8], &Vt[buf][t*8]);
  };

  stage(0, 0);
  __syncthreads();

  for (int kt = 0; kt < 16; ++kt) {
    int cur = kt & 1;
    if (kt < 15) stage(cur ^ 1, kt + 1);     // issue-early; barrier waits late

    // S^T = K @ Q^T : two 32x32 tiles (k 0-31, 32-63), contraction over d=64
    f32x16 s0, s1;
    #pragma unroll
    for (int r=0;r<16;++r) { s0[r]=0.f; s1[r]=0.f; }
    #pragma unroll
    for (int ds=0; ds<4; ++ds) {
      int sc0 = ds*2 + hi;
      {
        int krow = ql;
        short8 kf = *(const short8*)&Kt[cur][krow*64 + (sc0 ^ (krow & 7))*8];
        s0 = __builtin_amdgcn_mfma_f32_32x32x16_bf16(kf, qf[ds], s0, 0,0,0);
      }
      {
        int krow = 32 + ql;
        short8 kf = *(const short8*)&Kt[cur][krow*64 + (sc0 ^ (krow & 7))*8];
        s1 = __builtin_amdgcn_mfma_f32_32x32x16_bf16(kf, qf[ds], s1, 0,0,0);
      }
    }

    // row max: in-lane over 32 regs, then combine with partner lane (l^32)
    float pm = -1e30f;
    #pragma unroll
    for (int r=0;r<16;++r) pm = fmaxf(pm, fmaxf(s0[r], s1[r]));
    pm = fmaxf(pm, __shfl_xor(pm, 32));

    // defer-max: rescale only when row max grew by >8 (log2 domain; P <= 2^8)
    if (__any(pm > m + 8.f)) {
      float nm = fmaxf(m, pm);
      float fac = exp2fast(m - nm);
      m = nm;
      #pragma unroll
      for (int r=0;r<16;++r) {
        int qr = (r&3) + 8*(r>>2) + 4*hi;
        float facr = __shfl(fac, qr);      // lane qr holds fac for row q0+qr
        o0[r] *= facr; o1[r] *= facr; lacc[r] *= facr;
      }
    }

    // P = exp2(S - m); in-lane pack of adjacent-k pairs, partner exchange via
    // shfl_xor(32), per-lane select -> PV A-frag words (verified primitives only).
    float e[32];
    #pragma unroll
    for (int r=0;r<16;++r) { e[r] = exp2fast(s0[r] - m); e[16+r] = exp2fast(s1[r] - m); }
    uint32_t pw[16];
    #pragma unroll
    for (int sg=0; sg<4; ++sg) {
      const int rb = sg*8;
      uint32_t w01 = (uint32_t)f2bf_fast(e[rb+0]) | ((uint32_t)f2bf_fast(e[rb+1]) << 16);
      uint32_t w23 = (uint32_t)f2bf_fast(e[rb+2]) | ((uint32_t)f2bf_fast(e[rb+3]) << 16);
      uint32_t w45 = (uint32_t)f2bf_fast(e[rb+4]) | ((uint32_t)f2bf_fast(e[rb+5]) << 16);
      uint32_t w67 = (uint32_t)f2bf_fast(e[rb+6]) | ((uint32_t)f2bf_fast(e[rb+7]) << 16);
      uint32_t x01 = __shfl_xor(w01, 32);
      uint32_t x23 = __shfl_xor(w23, 32);
      uint32_t x45 = __shfl_xor(w45, 32);
      uint32_t x67 = __shfl_xor(w67, 32);
      pw[sg*4+0] = hi ? x45 : w01;   // k_local 0,1  (hi: 8,9)
      pw[sg*4+1] = hi ? x67 : w23;   // k_local 2,3  (hi: 10,11)
      pw[sg*4+2] = hi ? w45 : x01;   // k_local 4,5  (hi: 12,13)
      pw[sg*4+3] = hi ? w67 : x23;   // k_local 6,7  (hi: 14,15)
    }

    // O += P @ V ; l += P @ 1   (V[k][d] B-frags 16B-contiguous from V^T tile)
    #pragma unroll
    for (int ks=0; ks<4; ++ks) {
      short8 pf;
      #pragma unroll
      for (int j2=0;j2<4;++j2) {
        pf[j2*2]   = (short)(pw[ks*4+j2] & 0xFFFF);
        pf[j2*2+1] = (short)(pw[ks*4+j2] >> 16);
      }
      int sc0 = ks*2 + hi;
      {
        int vrow = ql;                     // d 0..31
        short8 vf = *(const short8*)&Vt[cur][vrow*64 + (sc0 ^ (vrow & 7))*8];
        o0 = __builtin_amdgcn_mfma_f32_32x32x16_bf16(pf, vf, o0, 0,0,0);
      }
      {
        int vrow = 32 + ql;                // d 32..63
        short8 vf = *(const short8*)&Vt[cur][vrow*64 + (sc0 ^ (vrow & 7))*8];
        o1 = __builtin_amdgcn_mfma_f32_32x32x16_bf16(pf, vf, o1, 0,0,0);
      }
      lacc = __builtin_amdgcn_mfma_f32_32x32x16_bf16(pf, ones, lacc, 0,0,0);
    }
    __syncthreads();
  }

  // epilogue: O rows q_r=(r&3)+8*(r>>2)+4*hi, cols d = {ql, 32+ql}; l rows align.
  #pragma unroll
  for (int r=0;r<16;++r) {
    float inv = 1.f / lacc[r];
    int qr = (r&3) + 8*(r>>2) + 4*hi;
    int row = b*N_ + q0 + qr;
    out[row*C_ + h*Dh + ql]      = f2bf(o0[r] * inv);
    out[row*C_ + h*Dh + 32 + ql] = f2bf(o1[r] * inv);
  }
}

// ---------------- host ----------------
extern "C" void kernel_launch(void* const* d_in, const int* in_sizes, int n_in,
                              void* d_out, int out_size, void* d_ws, size_t ws_size,
                              hipStream_t stream)
{
  const float* x      = (const float*)d_in[0];
  const float* W_qkv  = (const float*)d_in[1];
  const float* b_qkv  = (const float*)d_in[2];
  const float* kA     = (const float*)d_in[3];
  const float* kB     = (const float*)d_in[4];
  const float* vA     = (const float*)d_in[5];
  const float* vB     = (const float*)d_in[6];
  const float* W_proj = (const float*)d_in[7];
  const float* b_proj = (const float*)d_in[8];
  float* out = (float*)d_out;

  ushort* ws    = (ushort*)d_ws;
  ushort* xb    = ws;                    // 16,777,216 elems (reused as attn_out later)
  ushort* wqkvb = xb + 16777216;         // 3,145,728
  ushort* kvAb  = wqkvb + 3145728;       // 131,072  ([kA;vA] as 128x1024)
  ushort* kBb   = kvAb + 131072;         // 65,536   (pre-scaled by alpha/r)
  ushort* vBb   = kBb + 65536;           // 65,536   (pre-scaled by alpha/r)
  ushort* wprojb= vBb + 65536;           // 1,048,576
  ushort* tkv   = wprojb + 1048576;      // 2,097,152 ([x@kA^T | x@vA^T], 16384x128)
  ushort* qbuf  = tkv + 2097152;         // 16,777,216 each
  ushort* kbuf  = qbuf + 16777216;
  ushort* vbuf  = kbuf + 16777216;       // V^T layout (B,H,D,N)
  ushort* attn  = xb;                    // alias: xb dead after qkv/vT GEMMs

  const float ls = 1.0f / 64.0f;         // LORA_ALPHA / LORA_RANK

  auto cast = [&](const float* src, ushort* dst, int n, float scale) {
    int n4 = n >> 2;
    int blocks = (n4 + 255) / 256; if (blocks > 4096) blocks = 4096;
    cast_bf16_k<<<dim3(blocks), dim3(256), 0, stream>>>(src, dst, n4, scale);
  };
  cast(x,      xb,           16777216, 1.f);
  cast(W_qkv,  wqkvb,        3145728,  1.f);
  cast(kA,     kvAb,         65536,    1.f);
  cast(vA,     kvAb + 65536, 65536,    1.f);
  cast(kB,     kBb,          65536,    ls);
  cast(vB,     vBb,          65536,    ls);
  cast(W_proj, wprojb,       1048576,  1.f);

  // LoRA stage-1: tkv = xb @ [kA;vA]^T  (16384 x 128, K=1024)
  gemm128<0><<<dim3(128, 1), dim3(256), 0, stream>>>(
      xb, 1024, kvAb, 1024, nullptr, nullptr, nullptr, nullptr,
      tkv, nullptr, nullptr, nullptr, 0);

  // q,k GEMM + bias + fused LoRA-k tail, scatter to q/k (B,H,N,D); q pre-scaled
  gemm128<1><<<dim3(128, 16), dim3(256), 0, stream>>>(
      xb, 1024, wqkvb, 1024, b_qkv, tkv, kBb, nullptr,
      qbuf, kbuf, nullptr, nullptr, 0);

  // vT GEMM (swapped operands) + bias + fused LoRA-v tail -> vbuf (B,H,D,N)
  gemm128<3><<<dim3(8, 128), dim3(256), 0, stream>>>(
      wqkvb + 2048*1024, 1024, xb, 1024, b_qkv + 2048, vBb, tkv + 64, nullptr,
      nullptr, nullptr, vbuf, nullptr, 0);

  // flash attention (8-warp 32x32 swapped-QK) -> attn (B,N,C) bf16
  flash_attn32<<<dim3(1024), dim3(512), 0, stream>>>(qbuf, kbuf, vbuf, attn);

  // final projection -> fp32 d_out
  gemm128<2><<<dim3(128, 8), dim3(256), 0, stream>>>(
      attn, 1024, wprojb, 1024, b_proj, nullptr, nullptr, nullptr,
      nullptr, nullptr, nullptr, out, 1024);
}